// Round 11
// baseline (753.517 us; speedup 1.0000x reference)
//
#include <hip/hip_runtime.h>
#include <hip/hip_bf16.h>
#include <stdint.h>

#define NTILES 4
#define DMODEL 1024
#define DFF    4096
#define NTOK   16384

typedef __bf16 bf16x8 __attribute__((ext_vector_type(8)));
typedef float  f32x4  __attribute__((ext_vector_type(4)));

__device__ __forceinline__ uint16_t f2bf(float f) {
    union { float f; uint32_t u; } v; v.f = f;
    uint32_t u = v.u;
    uint32_t r = (u + 0x7fffu + ((u >> 16) & 1u)) >> 16;
    return (uint16_t)r;
}

#define STG(gptr, ldsoff) __builtin_amdgcn_global_load_lds( \
    (__attribute__((address_space(1))) void*)(gptr), \
    (__attribute__((address_space(3))) void*)(smem + (ldsoff)), 16, 0, 0)

// ---------------- Wup fp32 -> bf16 in MFMA-fragment layout + signature partials ----------
// Fragment (e, rb, kc) = rows rb*16..+15, k kc*32..+31, stored as 1KB: lane
// l = ((g&3)<<4)|r holds 16B granule (row rb*16+r, k = kc*32+(g&3)*8).
// grid (256 rb, 4 e), 128 threads (thread = granule column g, 8 k each).
__global__ void k_convup(const float* __restrict__ Wup, uint16_t* __restrict__ wupf,
                         double* __restrict__ partial) {
    int e = blockIdx.y, rb = blockIdx.x, g = threadIdx.x;    // g 0..127
    const float* src = Wup + ((size_t)e * DFF + rb * 16) * DMODEL + g * 8;
    uint16_t* dst = wupf + ((size_t)(e * 256 + rb) * 32 + (g >> 2)) * 512 + ((g & 3) << 4) * 8;
    double s0=0,s1=0,s2=0,s3=0,s4=0,s5=0,s6=0,s7=0;
    for (int r = 0; r < 16; ++r) {
        float4 v0 = *(const float4*)(src + (size_t)r * DMODEL);
        float4 v1 = *(const float4*)(src + (size_t)r * DMODEL + 4);
        ushort4 h0, h1;
        h0.x=f2bf(v0.x); h0.y=f2bf(v0.y); h0.z=f2bf(v0.z); h0.w=f2bf(v0.w);
        h1.x=f2bf(v1.x); h1.y=f2bf(v1.y); h1.z=f2bf(v1.z); h1.w=f2bf(v1.w);
        *(ushort4*)(dst + r * 8)     = h0;
        *(ushort4*)(dst + r * 8 + 4) = h1;
        s0+=v0.x; s1+=v0.y; s2+=v0.z; s3+=v0.w;
        s4+=v1.x; s5+=v1.y; s6+=v1.z; s7+=v1.w;
    }
    double* p = partial + ((size_t)e * DMODEL + g * 8) * 256 + rb;
    p[0*256]=s0; p[1*256]=s1; p[2*256]=s2; p[3*256]=s3;
    p[4*256]=s4; p[5*256]=s5; p[6*256]=s6; p[7*256]=s7;
}

// ---------------- Wdown fp32 -> bf16 fragment layout (no partials) -------------
// grid (64 rb, 4 e), 512 threads (g 0..511).
__global__ void k_convdown(const float* __restrict__ Wdown, uint16_t* __restrict__ wdownf) {
    int e = blockIdx.y, rb = blockIdx.x, g = threadIdx.x;
    const float* src = Wdown + ((size_t)e * DMODEL + rb * 16) * DFF + g * 8;
    uint16_t* dst = wdownf + ((size_t)(e * 64 + rb) * 128 + (g >> 2)) * 512 + ((g & 3) << 4) * 8;
    for (int r = 0; r < 16; ++r) {
        float4 v0 = *(const float4*)(src + (size_t)r * DFF);
        float4 v1 = *(const float4*)(src + (size_t)r * DFF + 4);
        ushort4 h0, h1;
        h0.x=f2bf(v0.x); h0.y=f2bf(v0.y); h0.z=f2bf(v0.z); h0.w=f2bf(v0.w);
        h1.x=f2bf(v1.x); h1.y=f2bf(v1.y); h1.z=f2bf(v1.z); h1.w=f2bf(v1.w);
        *(ushort4*)(dst + r * 8)     = h0;
        *(ushort4*)(dst + r * 8 + 4) = h1;
    }
}

// signature finalize (parallel) + zero expert counts
__global__ void k_sig_final(const double* __restrict__ partial, float* __restrict__ sig,
                            int* __restrict__ counts) {
    int b = blockIdx.x;
    int sub = threadIdx.x >> 5;
    int l32 = threadIdx.x & 31;
    int idx = b * 8 + sub;
    const double* p = partial + (size_t)idx * 256 + l32;
    double s = 0.0;
    #pragma unroll
    for (int i = 0; i < 8; ++i) s += p[i * 32];
    #pragma unroll
    for (int off = 16; off; off >>= 1) s += __shfl_xor(s, off);
    if (l32 == 0) sig[idx] = (s > 0.0) ? 1.0f : ((s < 0.0) ? -1.0f : 0.0f);
    if (b == 0 && threadIdx.x < NTILES) counts[threadIdx.x] = 0;
}

// ---------------- routing: scores, argmax, gate, xb (bf16 copy), buckets ----------------
__global__ void __launch_bounds__(256) k_route(const float* __restrict__ x,
                                               const float* __restrict__ sig,
                                               uint16_t* __restrict__ xb,
                                               float* __restrict__ gate_out,
                                               int* __restrict__ counts,
                                               int* __restrict__ perm) {
    __shared__ float sl[NTILES * DMODEL];
    for (int i = threadIdx.x; i < NTILES * DMODEL; i += 256) sl[i] = sig[i];
    __syncthreads();
    int wave = threadIdx.x >> 6, lane = threadIdx.x & 63;
    int tok = blockIdx.x * 4 + wave;
    const float* xr = x + (size_t)tok * DMODEL;
    float sc[NTILES] = {0.f, 0.f, 0.f, 0.f};
    for (int q = 0; q < 4; ++q) {
        int c = q * 256 + lane * 4;
        float4 xv = *(const float4*)(xr + c);
        #pragma unroll
        for (int t = 0; t < NTILES; ++t) {
            const float* st = sl + t * DMODEL + c;
            sc[t] += xv.x * st[0] + xv.y * st[1] + xv.z * st[2] + xv.w * st[3];
        }
        ushort4 h;
        h.x = f2bf(xv.x); h.y = f2bf(xv.y); h.z = f2bf(xv.z); h.w = f2bf(xv.w);
        *(ushort4*)(xb + (size_t)tok * DMODEL + c) = h;
    }
    #pragma unroll
    for (int t = 0; t < NTILES; ++t)
        for (int off = 32; off; off >>= 1) sc[t] += __shfl_xor(sc[t], off);
    int w = 0; float best = sc[0];
    if (sc[1] > best) { best = sc[1]; w = 1; }
    if (sc[2] > best) { best = sc[2]; w = 2; }
    if (sc[3] > best) { best = sc[3]; w = 3; }
    if (lane < NTILES) gate_out[(size_t)tok * NTILES + lane] = (lane == w) ? 1.0f : 0.0f;
    if (lane == 0) {
        int pos = atomicAdd(&counts[w], 1);
        perm[w * NTOK + pos] = tok;
    }
}

// ---------------- grouped NT GEMM: A in LDS (BM=128, BK=32, 3-ring), B direct ----------
// B loaded straight from fragment-ordered global (1KB coalesced per frag, L2-
// resident panels) -> per-tile LDS traffic 40KB vs 88KB (LDS-BW was the wall).
// 512 thr = 8 waves (2M x 4N), per-wave 64x64 (acc[4][4] -> AGPRs).
// XCD-bijective grid: bid%8 == y%8 -> all x-partners of an A-tile on one XCD.
// Per tile: {ds_read aF; deref bF; SB; STG A(t+2); lgkm0; SB; 16 MFMA; barrier}
// -> compiler's bF-wait = vmcnt(1): drains STG(t+1) on time, keeps STG(t+2) flying.
#define ASLOT 8192

template <int K, bool UP, int NX>
__global__ void __launch_bounds__(512, 2)
k_ffn10(const uint16_t* __restrict__ A, const uint16_t* __restrict__ Bf,
        const int* __restrict__ counts, const int* __restrict__ perm,
        uint16_t* __restrict__ hid_out, float* __restrict__ out) {
    constexpr int NOUT = UP ? DFF : DMODEL;
    constexpr int NT = K / 32;
    constexpr int NFRAG = NOUT / 16;
    __shared__ char smem[3 * ASLOT];

    // ---- XCD-bijective decode: xcd = bid%8 = y%8 ----
    const int bid = blockIdx.x;
    const int cph = bid & 7;
    const int q   = bid >> 3;
    const int x   = q & (NX - 1);
    const int y   = (q / NX) * 8 + cph;

    const int c0 = counts[0], c1 = counts[1], c2 = counts[2], c3 = counts[3];
    const int t0 = (c0+127)>>7, t1 = (c1+127)>>7, t2 = (c2+127)>>7, t3 = (c3+127)>>7;
    int e, yt, cnt, cofs;
    if (y < t0)                  { e=0; yt=y;             cnt=c0; cofs=0; }
    else if (y < t0+t1)          { e=1; yt=y-t0;          cnt=c1; cofs=c0; }
    else if (y < t0+t1+t2)       { e=2; yt=y-t0-t1;       cnt=c2; cofs=c0+c1; }
    else if (y < t0+t1+t2+t3)    { e=3; yt=y-t0-t1-t2;    cnt=c3; cofs=c0+c1+c2; }
    else return;
    const int base = yt * 128;
    const int bn0  = x * 256;

    const int tid = threadIdx.x;
    const int lane = tid & 63, wid = tid >> 6;
    const int wr = wid >> 2, wc = wid & 3;
    const int* permE = perm + e * NTOK;

    // ---- A staging (R10-verified, BK=32): thread -> row tid>>2, phys granule tid&3
    const int srow = tid >> 2;
    const int sg   = (tid & 3) ^ ((tid >> 3) & 3);   // inverse-swizzled source granule
    const uint16_t* gA;
    {
        int rr = base + srow;
        if constexpr (UP) {
            int tok = permE[(rr < cnt) ? rr : base];
            gA = A + (size_t)tok * K + sg * 8;
        } else {
            gA = A + (size_t)(cofs + rr) * K + sg * 8;
        }
    }
    const int ldsS = wid * 1024;     // staging dest (HW adds lane*16)

    // ---- A fragment read offsets (R10-verified swizzle, 64B rows)
    const int pg   = (lane >> 4) ^ (((lane & 15) >> 1) & 3);
    const int Aoff = (wr * 64 + (lane & 15)) * 64 + pg * 16;   // + m*1024

    // ---- B fragment base (direct global)
    const uint16_t* gBb = Bf + (size_t)(e * NFRAG + x * 16 + wc * 4) * NT * 512 + lane * 8;

    f32x4 acc[4][4];
    #pragma unroll
    for (int m = 0; m < 4; ++m)
        #pragma unroll
        for (int n = 0; n < 4; ++n) acc[m][n] = (f32x4){0.f, 0.f, 0.f, 0.f};

    // prologue: stage A tiles 0,1
    STG(gA,      0 * ASLOT + ldsS);
    STG(gA + 32, 1 * ASLOT + ldsS);
    asm volatile("s_waitcnt vmcnt(1)" ::: "memory");
    __builtin_amdgcn_sched_barrier(0);
    __builtin_amdgcn_s_barrier();

    int cs = 0;
    #pragma unroll 1
    for (int t = 0; t < NT; ++t) {
        const char* sp = smem + cs * ASLOT;
        const int ss = (cs == 0) ? 2 : cs - 1;     // (t+2)%3

        bf16x8 aF[4], bF[4];
        #pragma unroll
        for (int m = 0; m < 4; ++m) aF[m] = *(const bf16x8*)(sp + Aoff + m * 1024);
        #pragma unroll
        for (int n = 0; n < 4; ++n) bF[n] = *(const bf16x8*)(gBb + (size_t)n * NT * 512 + t * 512);
        __builtin_amdgcn_sched_barrier(0);         // pin bF issue above STG
        if (t + 2 < NT) STG(gA + (t + 2) * 32, ss * ASLOT + ldsS);
        asm volatile("s_waitcnt lgkmcnt(0)" ::: "memory");
        __builtin_amdgcn_sched_barrier(0);
        __builtin_amdgcn_s_setprio(1);
        #pragma unroll
        for (int m = 0; m < 4; ++m)
            #pragma unroll
            for (int n = 0; n < 4; ++n)
                acc[m][n] = __builtin_amdgcn_mfma_f32_16x16x32_bf16(aF[m], bF[n], acc[m][n], 0, 0, 0);
        __builtin_amdgcn_s_setprio(0);
        __builtin_amdgcn_s_barrier();
        cs = (cs == 2) ? 0 : cs + 1;
    }

    // epilogue: r = wr*64 + m*16 + (lane>>4)*4 + i, c = wc*64 + n*16 + (lane&15)
    #pragma unroll
    for (int m = 0; m < 4; ++m) {
        #pragma unroll
        for (int i = 0; i < 4; ++i) {
            int r  = wr * 64 + m * 16 + (lane >> 4) * 4 + i;
            int rr = base + r;
            if (rr < cnt) {
                if constexpr (UP) {
                    uint16_t* hr = hid_out + (size_t)(cofs + rr) * DFF + bn0 + wc * 64;
                    #pragma unroll
                    for (int n = 0; n < 4; ++n) {
                        float v = acc[m][n][i];
                        v = v > 0.f ? v : 0.f;
                        hr[n * 16 + (lane & 15)] = f2bf(v);
                    }
                } else {
                    float* orow = out + (size_t)permE[rr] * DMODEL + bn0 + wc * 64;
                    #pragma unroll
                    for (int n = 0; n < 4; ++n)
                        orow[n * 16 + (lane & 15)] = acc[m][n][i];
                }
            }
        }
    }
}

extern "C" void kernel_launch(void* const* d_in, const int* in_sizes, int n_in,
                              void* d_out, int out_size, void* d_ws, size_t ws_size,
                              hipStream_t stream) {
    const float* x     = (const float*)d_in[0];
    const float* Wup   = (const float*)d_in[1];
    const float* Wdown = (const float*)d_in[2];
    float* out  = (float*)d_out;
    float* gate = out + (size_t)NTOK * DMODEL;

    char* ws = (char*)d_ws;
    size_t off = 0;
    auto alloc = [&](size_t bytes) -> void* {
        void* p = ws + off;
        off += (bytes + 255) & ~(size_t)255;
        return p;
    };
    int*      counts  = (int*)alloc(NTILES * sizeof(int));
    float*    sig     = (float*)alloc((size_t)NTILES * DMODEL * sizeof(float));
    double*   partial = (double*)alloc((size_t)NTILES * DMODEL * 256 * sizeof(double));
    int*      perm    = (int*)alloc((size_t)NTILES * NTOK * sizeof(int));
    uint16_t* xb      = (uint16_t*)alloc((size_t)NTOK * DMODEL * 2);
    uint16_t* wupf    = (uint16_t*)alloc((size_t)NTILES * DFF * DMODEL * 2);
    uint16_t* wdownf  = (uint16_t*)alloc((size_t)NTILES * DMODEL * DFF * 2);
    uint16_t* hidden  = (uint16_t*)alloc(((size_t)NTOK + 1024) * DFF * 2);
    if (off > ws_size) return;

    hipLaunchKernelGGL(k_convup, dim3(256, 4), dim3(128), 0, stream, Wup, wupf, partial);
    hipLaunchKernelGGL(k_convdown, dim3(64, 4), dim3(512), 0, stream, Wdown, wdownf);
    hipLaunchKernelGGL(k_sig_final, dim3(512), dim3(256), 0, stream, partial, sig, counts);
    hipLaunchKernelGGL(k_route, dim3(NTOK / 4), dim3(256), 0, stream,
                       x, sig, xb, gate, counts, perm);
    // UP: x in 0..15, y up to 135 -> bid = y%8 + 8*(x + 16*(y/8)) < 2176
    hipLaunchKernelGGL((k_ffn10<DMODEL, true, 16>), dim3(2176), dim3(512), 0, stream,
                       xb, wupf, counts, perm, hidden, nullptr);
    // DOWN: x in 0..3, y up to 135 -> bid = y%8 + 8*(x + 4*(y/8)) < 544
    hipLaunchKernelGGL((k_ffn10<DFF, false, 4>), dim3(544), dim3(512), 0, stream,
                       hidden, wdownf, counts, perm, nullptr, out);
}

// Round 12
// 680.931 us; speedup vs baseline: 1.1066x; 1.1066x over previous
//
#include <hip/hip_runtime.h>
#include <hip/hip_bf16.h>
#include <stdint.h>

#define NTILES 4
#define DMODEL 1024
#define DFF    4096
#define NTOK   16384

typedef __bf16 bf16x8 __attribute__((ext_vector_type(8)));
typedef float  f32x4  __attribute__((ext_vector_type(4)));

__device__ __forceinline__ uint16_t f2bf(float f) {
    union { float f; uint32_t u; } v; v.f = f;
    uint32_t u = v.u;
    uint32_t r = (u + 0x7fffu + ((u >> 16) & 1u)) >> 16;
    return (uint16_t)r;
}

#define STG(gptr, ldsptr) __builtin_amdgcn_global_load_lds( \
    (__attribute__((address_space(1))) void*)(gptr), \
    (__attribute__((address_space(3))) void*)(ldsptr), 16, 0, 0)

// ---------------- fused converts: Wup->bf16 (+signature partials) AND Wdown->bf16 ----------------
__global__ void k_convert(const float* __restrict__ Wup, const float* __restrict__ Wdown,
                          uint16_t* __restrict__ wupb, uint16_t* __restrict__ wdownb,
                          double* __restrict__ partial) {
    int e = blockIdx.y, fb = blockIdx.x, tid = threadIdx.x;
    if (fb < 256) {
        const float* src = Wup + (size_t)e * DFF * DMODEL + (size_t)fb * 16 * DMODEL + tid * 4;
        uint16_t*    dst = wupb + (size_t)e * DFF * DMODEL + (size_t)fb * 16 * DMODEL + tid * 4;
        double s0 = 0, s1 = 0, s2 = 0, s3 = 0;
        #pragma unroll 4
        for (int i = 0; i < 16; ++i) {
            float4 v = *(const float4*)(src + (size_t)i * DMODEL);
            ushort4 h;
            h.x = f2bf(v.x); h.y = f2bf(v.y); h.z = f2bf(v.z); h.w = f2bf(v.w);
            *(ushort4*)(dst + (size_t)i * DMODEL) = h;
            s0 += v.x; s1 += v.y; s2 += v.z; s3 += v.w;
        }
        int c = tid * 4;
        double* p = partial + ((size_t)e * DMODEL + c) * 256 + fb;
        p[0 * 256] = s0; p[1 * 256] = s1; p[2 * 256] = s2; p[3 * 256] = s3;
    } else {
        int fb2 = fb - 256;
        const float* src = Wdown + (size_t)e * DMODEL * DFF + (size_t)fb2 * 16384 + tid * 4;
        uint16_t*    dst = wdownb + (size_t)e * DMODEL * DFF + (size_t)fb2 * 16384 + tid * 4;
        #pragma unroll 4
        for (int i = 0; i < 16; ++i) {
            float4 v = *(const float4*)(src + (size_t)i * 1024);
            ushort4 h;
            h.x = f2bf(v.x); h.y = f2bf(v.y); h.z = f2bf(v.z); h.w = f2bf(v.w);
            *(ushort4*)(dst + (size_t)i * 1024) = h;
        }
    }
}

// signature finalize (parallel) + zero expert counts
__global__ void k_sig_final(const double* __restrict__ partial, float* __restrict__ sig,
                            int* __restrict__ counts) {
    int b = blockIdx.x;
    int sub = threadIdx.x >> 5;
    int l32 = threadIdx.x & 31;
    int idx = b * 8 + sub;
    const double* p = partial + (size_t)idx * 256 + l32;
    double s = 0.0;
    #pragma unroll
    for (int i = 0; i < 8; ++i) s += p[i * 32];
    #pragma unroll
    for (int off = 16; off; off >>= 1) s += __shfl_xor(s, off);
    if (l32 == 0) sig[idx] = (s > 0.0) ? 1.0f : ((s < 0.0) ? -1.0f : 0.0f);
    if (b == 0 && threadIdx.x < NTILES) counts[threadIdx.x] = 0;
}

// ---------------- routing: scores, argmax, gate, xb (bf16 copy), buckets ----------------
__global__ void __launch_bounds__(256) k_route(const float* __restrict__ x,
                                               const float* __restrict__ sig,
                                               uint16_t* __restrict__ xb,
                                               float* __restrict__ gate_out,
                                               int* __restrict__ counts,
                                               int* __restrict__ perm) {
    __shared__ float sl[NTILES * DMODEL];
    for (int i = threadIdx.x; i < NTILES * DMODEL; i += 256) sl[i] = sig[i];
    __syncthreads();
    int wave = threadIdx.x >> 6, lane = threadIdx.x & 63;
    int tok = blockIdx.x * 4 + wave;
    const float* xr = x + (size_t)tok * DMODEL;
    float sc[NTILES] = {0.f, 0.f, 0.f, 0.f};
    for (int q = 0; q < 4; ++q) {
        int c = q * 256 + lane * 4;
        float4 xv = *(const float4*)(xr + c);
        #pragma unroll
        for (int t = 0; t < NTILES; ++t) {
            const float* st = sl + t * DMODEL + c;
            sc[t] += xv.x * st[0] + xv.y * st[1] + xv.z * st[2] + xv.w * st[3];
        }
        ushort4 h;
        h.x = f2bf(xv.x); h.y = f2bf(xv.y); h.z = f2bf(xv.z); h.w = f2bf(xv.w);
        *(ushort4*)(xb + (size_t)tok * DMODEL + c) = h;
    }
    #pragma unroll
    for (int t = 0; t < NTILES; ++t)
        for (int off = 32; off; off >>= 1) sc[t] += __shfl_xor(sc[t], off);
    int w = 0; float best = sc[0];
    if (sc[1] > best) { best = sc[1]; w = 1; }
    if (sc[2] > best) { best = sc[2]; w = 2; }
    if (sc[3] > best) { best = sc[3]; w = 3; }
    if (lane < NTILES) gate_out[(size_t)tok * NTILES + lane] = (lane == w) ? 1.0f : 0.0f;
    if (lane == 0) {
        int pos = atomicAdd(&counts[w], 1);
        perm[w * NTOK + pos] = tok;
    }
}

// ---------------- grouped NT GEMM: m97-faithful ----------------
// 128x128 tile, BK=32, 256 thr = 4 waves (2x2), per-wave 64x64 (acc[4][4]).
// Single 16KB LDS buffer (A 8KB + B 8KB), plain 2-barrier K-loop:
//   { barrier | STG x4 | barrier(compiler drains vmcnt+lgkm) | ds_read | MFMA }.
// NO inline-asm waits / setprio / rings — occupancy (~3 blocks/CU) provides the
// overlap (m97/m114: 874-912 TF, MfmaUtil 36-37% on this chip).
// Swizzle (verified R10/R11, 64B rows): phys granule p at row r holds logical
// g = p ^ ((r>>1)&3); staging tid -> row tid>>2, p = tid&3, src g = (tid&3)^((tid>>3)&3).
template <int K, bool UP>
__global__ void __launch_bounds__(256)
k_ffn11(const uint16_t* __restrict__ A, const uint16_t* __restrict__ Bw,
        const int* __restrict__ counts, const int* __restrict__ perm,
        uint16_t* __restrict__ hid_out, float* __restrict__ out) {
    constexpr int NOUT = UP ? DFF : DMODEL;
    constexpr int NT = K / 32;
    __shared__ char smem[16384];

    const int e = blockIdx.z;
    const int c0 = counts[0], c1 = counts[1], c2 = counts[2];
    const int cnt = counts[e];
    const int cofs = (e > 0 ? c0 : 0) + (e > 1 ? c1 : 0) + (e > 2 ? c2 : 0);
    const int base = blockIdx.y * 128;
    if (base >= cnt) return;
    const int bn0 = blockIdx.x * 128;
    const int tid = threadIdx.x;
    const int lane = tid & 63, wid = tid >> 6;     // 4 waves
    const int wr = wid >> 1, wc = wid & 1;
    const int* permE = perm + e * NTOK;

    // staging: instr j covers rows j*64 + (tid>>2); source granule inverse-swizzled
    const int srow = tid >> 2;                     // 0..63
    const int sg   = (tid & 3) ^ ((tid >> 3) & 3);
    const uint16_t* gA[2];
    const uint16_t* gB[2];
    #pragma unroll
    for (int j = 0; j < 2; ++j) {
        int r  = j * 64 + srow;
        int rr = base + r;
        if constexpr (UP) {
            int tok = permE[(rr < cnt) ? rr : base];
            gA[j] = A + (size_t)tok * K + sg * 8;
        } else {
            gA[j] = A + (size_t)(cofs + rr) * K + sg * 8;
        }
        gB[j] = Bw + ((size_t)e * NOUT + bn0 + r) * K + sg * 8;
    }
    // LDS staging dest bases (wave-uniform; HW adds lane*16)
    char* stA0 = smem + wid * 1024;                // rows 0..63
    char* stA1 = smem + 4096 + wid * 1024;         // rows 64..127
    char* stB0 = smem + 8192 + wid * 1024;
    char* stB1 = smem + 12288 + wid * 1024;

    // fragment read offsets (verified swizzle)
    const int pg   = (lane >> 4) ^ (((lane & 15) >> 1) & 3);
    const int Aoff = (wr * 64 + (lane & 15)) * 64 + pg * 16;          // + m*1024
    const int Boff = 8192 + (wc * 64 + (lane & 15)) * 64 + pg * 16;   // + n*1024

    f32x4 acc[4][4];
    #pragma unroll
    for (int m = 0; m < 4; ++m)
        #pragma unroll
        for (int n = 0; n < 4; ++n) acc[m][n] = (f32x4){0.f, 0.f, 0.f, 0.f};

    #pragma unroll 1
    for (int t = 0; t < NT; ++t) {
        if (t) __syncthreads();        // prior reads done before overwrite
        STG(gA[0] + t * 32, stA0);
        STG(gA[1] + t * 32, stA1);
        STG(gB[0] + t * 32, stB0);
        STG(gB[1] + t * 32, stB1);
        __syncthreads();               // compiler drains vmcnt(0): tile landed

        bf16x8 aF[4], bF[4];
        #pragma unroll
        for (int m = 0; m < 4; ++m) aF[m] = *(const bf16x8*)(smem + Aoff + m * 1024);
        #pragma unroll
        for (int n = 0; n < 4; ++n) bF[n] = *(const bf16x8*)(smem + Boff + n * 1024);
        #pragma unroll
        for (int m = 0; m < 4; ++m)
            #pragma unroll
            for (int n = 0; n < 4; ++n)
                acc[m][n] = __builtin_amdgcn_mfma_f32_16x16x32_bf16(aF[m], bF[n], acc[m][n], 0, 0, 0);
    }

    // epilogue: r = wr*64 + m*16 + (lane>>4)*4 + i, c = wc*64 + n*16 + (lane&15)
    #pragma unroll
    for (int m = 0; m < 4; ++m) {
        #pragma unroll
        for (int i = 0; i < 4; ++i) {
            int r  = wr * 64 + m * 16 + (lane >> 4) * 4 + i;
            int rr = base + r;
            if (rr < cnt) {
                if constexpr (UP) {
                    uint16_t* hr = hid_out + (size_t)(cofs + rr) * DFF + bn0 + wc * 64;
                    #pragma unroll
                    for (int n = 0; n < 4; ++n) {
                        float v = acc[m][n][i];
                        v = v > 0.f ? v : 0.f;
                        hr[n * 16 + (lane & 15)] = f2bf(v);
                    }
                } else {
                    float* orow = out + (size_t)permE[rr] * DMODEL + bn0 + wc * 64;
                    #pragma unroll
                    for (int n = 0; n < 4; ++n)
                        orow[n * 16 + (lane & 15)] = acc[m][n][i];
                }
            }
        }
    }
}

extern "C" void kernel_launch(void* const* d_in, const int* in_sizes, int n_in,
                              void* d_out, int out_size, void* d_ws, size_t ws_size,
                              hipStream_t stream) {
    const float* x     = (const float*)d_in[0];
    const float* Wup   = (const float*)d_in[1];
    const float* Wdown = (const float*)d_in[2];
    float* out  = (float*)d_out;
    float* gate = out + (size_t)NTOK * DMODEL;

    char* ws = (char*)d_ws;
    size_t off = 0;
    auto alloc = [&](size_t bytes) -> void* {
        void* p = ws + off;
        off += (bytes + 255) & ~(size_t)255;
        return p;
    };
    int*      counts  = (int*)alloc(NTILES * sizeof(int));
    float*    sig     = (float*)alloc((size_t)NTILES * DMODEL * sizeof(float));
    double*   partial = (double*)alloc((size_t)NTILES * DMODEL * 256 * sizeof(double));
    int*      perm    = (int*)alloc((size_t)NTILES * NTOK * sizeof(int));
    uint16_t* xb      = (uint16_t*)alloc((size_t)NTOK * DMODEL * 2);
    uint16_t* wupb    = (uint16_t*)alloc((size_t)NTILES * DFF * DMODEL * 2);
    uint16_t* wdownb  = (uint16_t*)alloc((size_t)NTILES * DMODEL * DFF * 2);
    uint16_t* hidden  = (uint16_t*)alloc(((size_t)NTOK + 1024) * DFF * 2);
    if (off > ws_size) return;

    hipLaunchKernelGGL(k_convert, dim3(512, 4), dim3(256), 0, stream,
                       Wup, Wdown, wupb, wdownb, partial);
    hipLaunchKernelGGL(k_sig_final, dim3(512), dim3(256), 0, stream, partial, sig, counts);
    hipLaunchKernelGGL(k_route, dim3(NTOK / 4), dim3(256), 0, stream,
                       x, sig, xb, gate, counts, perm);
    hipLaunchKernelGGL((k_ffn11<DMODEL, true>), dim3(DFF / 128, NTOK / 128, NTILES),
                       dim3(256), 0, stream, xb, wupb, counts, perm, hidden, nullptr);
    hipLaunchKernelGGL((k_ffn11<DFF, false>), dim3(DMODEL / 128, NTOK / 128, NTILES),
                       dim3(256), 0, stream, hidden, wdownb, counts, perm, nullptr, out);
}

// Round 13
// 600.492 us; speedup vs baseline: 1.2548x; 1.1340x over previous
//
#include <hip/hip_runtime.h>
#include <hip/hip_bf16.h>
#include <stdint.h>

#define NTILES 4
#define DMODEL 1024
#define DFF    4096
#define NTOK   16384

typedef __bf16 bf16x8 __attribute__((ext_vector_type(8)));
typedef float  f32x4  __attribute__((ext_vector_type(4)));

__device__ __forceinline__ uint16_t f2bf(float f) {
    union { float f; uint32_t u; } v; v.f = f;
    uint32_t u = v.u;
    uint32_t r = (u + 0x7fffu + ((u >> 16) & 1u)) >> 16;
    return (uint16_t)r;
}

#define STG(gptr, ldsoff) __builtin_amdgcn_global_load_lds( \
    (__attribute__((address_space(1))) void*)(gptr), \
    (__attribute__((address_space(3))) void*)(smem + (ldsoff)), 16, 0, 0)

// ---------------- fused converts: Wup->bf16 (+signature partials) AND Wdown->bf16 ----------
// Partial layout [fb][e*1024+c] -> each thread stores 4 contiguous doubles
// (coalesced across the block); previous [e][c][fb] layout scattered 8B stores
// 8KB apart (10-20x write amplification on 8.4MB).
__global__ void k_convert(const float* __restrict__ Wup, const float* __restrict__ Wdown,
                          uint16_t* __restrict__ wupb, uint16_t* __restrict__ wdownb,
                          double* __restrict__ partial) {
    int e = blockIdx.y, fb = blockIdx.x, tid = threadIdx.x;
    if (fb < 256) {
        const float* src = Wup + (size_t)e * DFF * DMODEL + (size_t)fb * 16 * DMODEL + tid * 4;
        uint16_t*    dst = wupb + (size_t)e * DFF * DMODEL + (size_t)fb * 16 * DMODEL + tid * 4;
        double s0 = 0, s1 = 0, s2 = 0, s3 = 0;
        #pragma unroll 4
        for (int i = 0; i < 16; ++i) {
            float4 v = *(const float4*)(src + (size_t)i * DMODEL);
            ushort4 h;
            h.x = f2bf(v.x); h.y = f2bf(v.y); h.z = f2bf(v.z); h.w = f2bf(v.w);
            *(ushort4*)(dst + (size_t)i * DMODEL) = h;
            s0 += v.x; s1 += v.y; s2 += v.z; s3 += v.w;
        }
        double* p = partial + (size_t)fb * (NTILES * DMODEL) + e * DMODEL + tid * 4;
        p[0] = s0; p[1] = s1; p[2] = s2; p[3] = s3;
    } else {
        int fb2 = fb - 256;
        const float* src = Wdown + (size_t)e * DMODEL * DFF + (size_t)fb2 * 16384 + tid * 4;
        uint16_t*    dst = wdownb + (size_t)e * DMODEL * DFF + (size_t)fb2 * 16384 + tid * 4;
        #pragma unroll 4
        for (int i = 0; i < 16; ++i) {
            float4 v = *(const float4*)(src + (size_t)i * 1024);
            ushort4 h;
            h.x = f2bf(v.x); h.y = f2bf(v.y); h.z = f2bf(v.z); h.w = f2bf(v.w);
            *(ushort4*)(dst + (size_t)i * 1024) = h;
        }
    }
}

// signature finalize: one thread per (e,c) column; reads coalesced across gid
// per fb step.  Also zeros expert counts.
__global__ void k_sig_final(const double* __restrict__ partial, float* __restrict__ sig,
                            int* __restrict__ counts) {
    int gid = blockIdx.x * 256 + threadIdx.x;    // 0..4095
    double s = 0.0;
    #pragma unroll 8
    for (int fb = 0; fb < 256; ++fb) s += partial[(size_t)fb * (NTILES * DMODEL) + gid];
    sig[gid] = (s > 0.0) ? 1.0f : ((s < 0.0) ? -1.0f : 0.0f);
    if (gid < NTILES) counts[gid] = 0;
}

// ---------------- routing: scores, argmax, gate, xb (bf16 copy), buckets ----------------
__global__ void __launch_bounds__(256) k_route(const float* __restrict__ x,
                                               const float* __restrict__ sig,
                                               uint16_t* __restrict__ xb,
                                               float* __restrict__ gate_out,
                                               int* __restrict__ counts,
                                               int* __restrict__ perm) {
    __shared__ float sl[NTILES * DMODEL];
    for (int i = threadIdx.x; i < NTILES * DMODEL; i += 256) sl[i] = sig[i];
    __syncthreads();
    int wave = threadIdx.x >> 6, lane = threadIdx.x & 63;
    int tok = blockIdx.x * 4 + wave;
    const float* xr = x + (size_t)tok * DMODEL;
    float sc[NTILES] = {0.f, 0.f, 0.f, 0.f};
    for (int q = 0; q < 4; ++q) {
        int c = q * 256 + lane * 4;
        float4 xv = *(const float4*)(xr + c);
        #pragma unroll
        for (int t = 0; t < NTILES; ++t) {
            const float* st = sl + t * DMODEL + c;
            sc[t] += xv.x * st[0] + xv.y * st[1] + xv.z * st[2] + xv.w * st[3];
        }
        ushort4 h;
        h.x = f2bf(xv.x); h.y = f2bf(xv.y); h.z = f2bf(xv.z); h.w = f2bf(xv.w);
        *(ushort4*)(xb + (size_t)tok * DMODEL + c) = h;
    }
    #pragma unroll
    for (int t = 0; t < NTILES; ++t)
        for (int off = 32; off; off >>= 1) sc[t] += __shfl_xor(sc[t], off);
    int w = 0; float best = sc[0];
    if (sc[1] > best) { best = sc[1]; w = 1; }
    if (sc[2] > best) { best = sc[2]; w = 2; }
    if (sc[3] > best) { best = sc[3]; w = 3; }
    if (lane < NTILES) gate_out[(size_t)tok * NTILES + lane] = (lane == w) ? 1.0f : 0.0f;
    if (lane == 0) {
        int pos = atomicAdd(&counts[w], 1);
        perm[w * NTOK + pos] = tok;
    }
}

// ---------------- grouped NT GEMM: 128x256 tile, BK=32, 3-slot ring, 2 blocks/CU ----------
// R10's verified best-total GEMM, byte-identical.
#define SLOT9 24576

template <int K, bool UP>
__global__ void __launch_bounds__(512, 2)
k_ffn9(const uint16_t* __restrict__ A, const uint16_t* __restrict__ Bw,
       const int* __restrict__ counts, const int* __restrict__ perm,
       uint16_t* __restrict__ hid_out, float* __restrict__ out) {
    constexpr int NOUT = UP ? DFF : DMODEL;
    constexpr int NT = K / 32;
    extern __shared__ char smem[];

    const int e = blockIdx.z;
    const int c0 = counts[0], c1 = counts[1], c2 = counts[2];
    const int cnt = counts[e];
    const int cofs = (e > 0 ? c0 : 0) + (e > 1 ? c1 : 0) + (e > 2 ? c2 : 0);
    const int base = blockIdx.y * 128;
    if (base >= cnt) return;
    const int bn0 = blockIdx.x * 256;
    const int tid = threadIdx.x;
    const int lane = tid & 63, wid = tid >> 6;
    const int wr = wid >> 2, wc = wid & 3;        // 2M x 4N, per-wave 64x64
    const int* permE = perm + e * NTOK;

    // ---- staging decode: row = tid>>2, pg = tid&3, logical granule g
    const int srow = tid >> 2;                    // 0..127
    const int sg   = (tid & 3) ^ ((tid >> 3) & 3);
    const uint16_t* gA;
    {
        int rr = base + srow;
        if constexpr (UP) {
            int tok = permE[(rr < cnt) ? rr : base];
            gA = A + (size_t)tok * K + sg * 8;
        } else {
            gA = A + (size_t)(cofs + rr) * K + sg * 8;
        }
    }
    const uint16_t* gB[2];
    #pragma unroll
    for (int j = 0; j < 2; ++j)
        gB[j] = Bw + ((size_t)e * NOUT + bn0 + j * 128 + srow) * K + sg * 8;

    const int ldsA = wid * 1024;                  // A region [0, 8192)
    const int ldsB = 8192 + wid * 1024;           // B region [8192, 24576), + j*8192

    const int pg  = (lane >> 4) ^ (((lane & 15) >> 1) & 3);
    const int Aoff = (wr * 64 + (lane & 15)) * 64 + pg * 16;          // + m*1024
    const int Boff = 8192 + (wc * 64 + (lane & 15)) * 64 + pg * 16;   // + n*1024

    f32x4 acc[4][4];
    #pragma unroll
    for (int m = 0; m < 4; ++m)
        #pragma unroll
        for (int n = 0; n < 4; ++n) acc[m][n] = (f32x4){0.f, 0.f, 0.f, 0.f};

    // prologue: stage tiles 0,1 -> slots 0,1 (3 loads each)
    #pragma unroll
    for (int tt = 0; tt < 2; ++tt) {
        STG(gA + tt * 32,    tt * SLOT9 + ldsA);
        STG(gB[0] + tt * 32, tt * SLOT9 + ldsB);
        STG(gB[1] + tt * 32, tt * SLOT9 + ldsB + 8192);
    }
    asm volatile("s_waitcnt vmcnt(3)" ::: "memory");
    __builtin_amdgcn_sched_barrier(0);
    __builtin_amdgcn_s_barrier();

    int cs = 0;
    #pragma unroll 1
    for (int t = 0; t < NT; ++t) {
        const char* sp = smem + cs * SLOT9;
        const bool pre = (t + 2) < NT;
        const int ss = ((cs == 0) ? 2 : cs - 1) * SLOT9;   // slot of (t+2)%3

        bf16x8 aF[4], bF[4];
        #pragma unroll
        for (int m = 0; m < 4; ++m) aF[m] = *(const bf16x8*)(sp + Aoff + m * 1024);
        #pragma unroll
        for (int n = 0; n < 4; ++n) bF[n] = *(const bf16x8*)(sp + Boff + n * 1024);
        if (pre) {
            STG(gA + (t + 2) * 32,    ss + ldsA);
            STG(gB[0] + (t + 2) * 32, ss + ldsB);
            STG(gB[1] + (t + 2) * 32, ss + ldsB + 8192);
        }
        __builtin_amdgcn_s_barrier();
        asm volatile("s_waitcnt lgkmcnt(0)" ::: "memory");
        __builtin_amdgcn_sched_barrier(0);
        __builtin_amdgcn_s_setprio(1);
        #pragma unroll
        for (int m = 0; m < 4; ++m)
            #pragma unroll
            for (int n = 0; n < 4; ++n)
                acc[m][n] = __builtin_amdgcn_mfma_f32_16x16x32_bf16(aF[m], bF[n], acc[m][n], 0, 0, 0);
        __builtin_amdgcn_s_setprio(0);
        if (pre) { asm volatile("s_waitcnt vmcnt(3)" ::: "memory"); }
        else     { asm volatile("s_waitcnt vmcnt(0)" ::: "memory"); }
        __builtin_amdgcn_sched_barrier(0);
        __builtin_amdgcn_s_barrier();
        cs = (cs == 2) ? 0 : cs + 1;
    }

    // epilogue: r = wr*64 + m*16 + (lane>>4)*4 + i, c = wc*64 + n*16 + (lane&15)
    #pragma unroll
    for (int m = 0; m < 4; ++m) {
        #pragma unroll
        for (int i = 0; i < 4; ++i) {
            int r  = wr * 64 + m * 16 + (lane >> 4) * 4 + i;
            int rr = base + r;
            if (rr < cnt) {
                if constexpr (UP) {
                    uint16_t* hr = hid_out + (size_t)(cofs + rr) * DFF + bn0 + wc * 64;
                    #pragma unroll
                    for (int n = 0; n < 4; ++n) {
                        float v = acc[m][n][i];
                        v = v > 0.f ? v : 0.f;
                        hr[n * 16 + (lane & 15)] = f2bf(v);
                    }
                } else {
                    float* orow = out + (size_t)permE[rr] * DMODEL + bn0 + wc * 64;
                    #pragma unroll
                    for (int n = 0; n < 4; ++n)
                        orow[n * 16 + (lane & 15)] = acc[m][n][i];
                }
            }
        }
    }
}

extern "C" void kernel_launch(void* const* d_in, const int* in_sizes, int n_in,
                              void* d_out, int out_size, void* d_ws, size_t ws_size,
                              hipStream_t stream) {
    const float* x     = (const float*)d_in[0];
    const float* Wup   = (const float*)d_in[1];
    const float* Wdown = (const float*)d_in[2];
    float* out  = (float*)d_out;
    float* gate = out + (size_t)NTOK * DMODEL;

    char* ws = (char*)d_ws;
    size_t off = 0;
    auto alloc = [&](size_t bytes) -> void* {
        void* p = ws + off;
        off += (bytes + 255) & ~(size_t)255;
        return p;
    };
    int*      counts  = (int*)alloc(NTILES * sizeof(int));
    float*    sig     = (float*)alloc((size_t)NTILES * DMODEL * sizeof(float));
    double*   partial = (double*)alloc((size_t)256 * NTILES * DMODEL * sizeof(double));
    int*      perm    = (int*)alloc((size_t)NTILES * NTOK * sizeof(int));
    uint16_t* xb      = (uint16_t*)alloc((size_t)NTOK * DMODEL * 2);
    uint16_t* wupb    = (uint16_t*)alloc((size_t)NTILES * DFF * DMODEL * 2);
    uint16_t* wdownb  = (uint16_t*)alloc((size_t)NTILES * DMODEL * DFF * 2);
    uint16_t* hidden  = (uint16_t*)alloc(((size_t)NTOK + 1024) * DFF * 2);
    if (off > ws_size) return;

    hipFuncSetAttribute((const void*)&k_ffn9<DMODEL, true>,
                        hipFuncAttributeMaxDynamicSharedMemorySize, 3 * SLOT9);
    hipFuncSetAttribute((const void*)&k_ffn9<DFF, false>,
                        hipFuncAttributeMaxDynamicSharedMemorySize, 3 * SLOT9);

    hipLaunchKernelGGL(k_convert, dim3(512, 4), dim3(256), 0, stream,
                       Wup, Wdown, wupb, wdownb, partial);
    hipLaunchKernelGGL(k_sig_final, dim3(16), dim3(256), 0, stream, partial, sig, counts);
    hipLaunchKernelGGL(k_route, dim3(NTOK / 4), dim3(256), 0, stream,
                       x, sig, xb, gate, counts, perm);
    hipLaunchKernelGGL((k_ffn9<DMODEL, true>), dim3(DFF / 256, NTOK / 128, NTILES),
                       dim3(512), 3 * SLOT9, stream, xb, wupb, counts, perm, hidden, nullptr);
    hipLaunchKernelGGL((k_ffn9<DFF, false>), dim3(DMODEL / 256, NTOK / 128, NTILES),
                       dim3(512), 3 * SLOT9, stream, hidden, wdownb, counts, perm, nullptr, out);
}

// Round 14
// 586.778 us; speedup vs baseline: 1.2842x; 1.0234x over previous
//
#include <hip/hip_runtime.h>
#include <hip/hip_bf16.h>
#include <stdint.h>

#define NTILES 4
#define DMODEL 1024
#define DFF    4096
#define NTOK   16384
#define YGEMM  128      // UP grid: y<128 GEMM, y>=128 Wdown-convert chunks

typedef __bf16 bf16x8 __attribute__((ext_vector_type(8)));
typedef float  f32x4  __attribute__((ext_vector_type(4)));

__device__ __forceinline__ uint16_t f2bf(float f) {
    union { float f; uint32_t u; } v; v.f = f;
    uint32_t u = v.u;
    uint32_t r = (u + 0x7fffu + ((u >> 16) & 1u)) >> 16;
    return (uint16_t)r;
}

#define STG(gptr, ldsoff) __builtin_amdgcn_global_load_lds( \
    (__attribute__((address_space(1))) void*)(gptr), \
    (__attribute__((address_space(3))) void*)(smem + (ldsoff)), 16, 0, 0)

// ---------------- Wup fp32->bf16 convert + signature partials (coalesced layout) ----------
__global__ void k_convert(const float* __restrict__ Wup, uint16_t* __restrict__ wupb,
                          double* __restrict__ partial) {
    int e = blockIdx.y, fb = blockIdx.x, tid = threadIdx.x;
    const float* src = Wup + (size_t)e * DFF * DMODEL + (size_t)fb * 16 * DMODEL + tid * 4;
    uint16_t*    dst = wupb + (size_t)e * DFF * DMODEL + (size_t)fb * 16 * DMODEL + tid * 4;
    double s0 = 0, s1 = 0, s2 = 0, s3 = 0;
    #pragma unroll 4
    for (int i = 0; i < 16; ++i) {
        float4 v = *(const float4*)(src + (size_t)i * DMODEL);
        ushort4 h;
        h.x = f2bf(v.x); h.y = f2bf(v.y); h.z = f2bf(v.z); h.w = f2bf(v.w);
        *(ushort4*)(dst + (size_t)i * DMODEL) = h;
        s0 += v.x; s1 += v.y; s2 += v.z; s3 += v.w;
    }
    double* p = partial + (size_t)fb * (NTILES * DMODEL) + e * DMODEL + tid * 4;
    p[0] = s0; p[1] = s1; p[2] = s2; p[3] = s3;
}

// signature finalize (coalesced reads) + zero expert counts
__global__ void k_sig_final(const double* __restrict__ partial, float* __restrict__ sig,
                            int* __restrict__ counts) {
    int gid = blockIdx.x * 256 + threadIdx.x;    // 0..4095
    double s = 0.0;
    #pragma unroll 8
    for (int fb = 0; fb < 256; ++fb) s += partial[(size_t)fb * (NTILES * DMODEL) + gid];
    sig[gid] = (s > 0.0) ? 1.0f : ((s < 0.0) ? -1.0f : 0.0f);
    if (gid < NTILES) counts[gid] = 0;
}

// ---------------- routing: 16 tokens/block (sig staging amortized 4x) ----------------
__global__ void __launch_bounds__(256) k_route(const float* __restrict__ x,
                                               const float* __restrict__ sig,
                                               uint16_t* __restrict__ xb,
                                               float* __restrict__ gate_out,
                                               int* __restrict__ counts,
                                               int* __restrict__ perm) {
    __shared__ float sl[NTILES * DMODEL];
    for (int i = threadIdx.x; i < NTILES * DMODEL; i += 256) sl[i] = sig[i];
    __syncthreads();
    int wave = threadIdx.x >> 6, lane = threadIdx.x & 63;
    #pragma unroll 1
    for (int tk = 0; tk < 4; ++tk) {
        int tok = blockIdx.x * 16 + wave * 4 + tk;
        const float* xr = x + (size_t)tok * DMODEL;
        float sc[NTILES] = {0.f, 0.f, 0.f, 0.f};
        for (int q = 0; q < 4; ++q) {
            int c = q * 256 + lane * 4;
            float4 xv = *(const float4*)(xr + c);
            #pragma unroll
            for (int t = 0; t < NTILES; ++t) {
                const float* st = sl + t * DMODEL + c;
                sc[t] += xv.x * st[0] + xv.y * st[1] + xv.z * st[2] + xv.w * st[3];
            }
            ushort4 h;
            h.x = f2bf(xv.x); h.y = f2bf(xv.y); h.z = f2bf(xv.z); h.w = f2bf(xv.w);
            *(ushort4*)(xb + (size_t)tok * DMODEL + c) = h;
        }
        #pragma unroll
        for (int t = 0; t < NTILES; ++t)
            for (int off = 32; off; off >>= 1) sc[t] += __shfl_xor(sc[t], off);
        int w = 0; float best = sc[0];
        if (sc[1] > best) { best = sc[1]; w = 1; }
        if (sc[2] > best) { best = sc[2]; w = 2; }
        if (sc[3] > best) { best = sc[3]; w = 3; }
        if (lane < NTILES) gate_out[(size_t)tok * NTILES + lane] = (lane == w) ? 1.0f : 0.0f;
        if (lane == 0) {
            int pos = atomicAdd(&counts[w], 1);
            perm[w * NTOK + pos] = tok;
        }
    }
}

// ---------------- grouped NT GEMM: 128x256, BK=32, 3-slot ring, 2 blocks/CU ----------
// R13's verified GEMM, byte-identical, plus (UP only) fused Wdown-convert blocks
// at blockIdx.y >= YGEMM — independent streaming rides UP's spare HBM bandwidth.
#define SLOT9 24576

template <int K, bool UP>
__global__ void __launch_bounds__(512, 2)
k_ffn9(const uint16_t* __restrict__ A, const uint16_t* __restrict__ Bw,
       const int* __restrict__ counts, const int* __restrict__ perm,
       uint16_t* __restrict__ hid_out, float* __restrict__ out,
       const float* __restrict__ cvtSrc, uint16_t* __restrict__ cvtDst) {
    constexpr int NOUT = UP ? DFF : DMODEL;
    constexpr int NT = K / 32;
    extern __shared__ char smem[];

    if constexpr (UP) {
        if (blockIdx.y >= YGEMM) {
            // Wdown fp32->bf16 convert chunk: 512 thr x 16 elems
            int chunk = ((int)(blockIdx.z * 32 + (blockIdx.y - YGEMM))) * 16 + blockIdx.x;
            const float* src = cvtSrc + (size_t)chunk * 8192 + threadIdx.x * 4;
            uint16_t*    dst = cvtDst + (size_t)chunk * 8192 + threadIdx.x * 4;
            #pragma unroll
            for (int i = 0; i < 4; ++i) {
                float4 v = *(const float4*)(src + i * 2048);
                ushort4 h;
                h.x = f2bf(v.x); h.y = f2bf(v.y); h.z = f2bf(v.z); h.w = f2bf(v.w);
                *(ushort4*)(dst + i * 2048) = h;
            }
            return;
        }
    }

    const int e = blockIdx.z;
    const int c0 = counts[0], c1 = counts[1], c2 = counts[2];
    const int cnt = counts[e];
    const int cofs = (e > 0 ? c0 : 0) + (e > 1 ? c1 : 0) + (e > 2 ? c2 : 0);
    const int base = blockIdx.y * 128;
    if (base >= cnt) return;
    const int bn0 = blockIdx.x * 256;
    const int tid = threadIdx.x;
    const int lane = tid & 63, wid = tid >> 6;
    const int wr = wid >> 2, wc = wid & 3;        // 2M x 4N, per-wave 64x64
    const int* permE = perm + e * NTOK;

    // ---- staging decode: row = tid>>2, pg = tid&3, logical granule g
    const int srow = tid >> 2;                    // 0..127
    const int sg   = (tid & 3) ^ ((tid >> 3) & 3);
    const uint16_t* gA;
    {
        int rr = base + srow;
        if constexpr (UP) {
            int tok = permE[(rr < cnt) ? rr : base];
            gA = A + (size_t)tok * K + sg * 8;
        } else {
            gA = A + (size_t)(cofs + rr) * K + sg * 8;
        }
    }
    const uint16_t* gB[2];
    #pragma unroll
    for (int j = 0; j < 2; ++j)
        gB[j] = Bw + ((size_t)e * NOUT + bn0 + j * 128 + srow) * K + sg * 8;

    const int ldsA = wid * 1024;                  // A region [0, 8192)
    const int ldsB = 8192 + wid * 1024;           // B region [8192, 24576), + j*8192

    const int pg  = (lane >> 4) ^ (((lane & 15) >> 1) & 3);
    const int Aoff = (wr * 64 + (lane & 15)) * 64 + pg * 16;          // + m*1024
    const int Boff = 8192 + (wc * 64 + (lane & 15)) * 64 + pg * 16;   // + n*1024

    f32x4 acc[4][4];
    #pragma unroll
    for (int m = 0; m < 4; ++m)
        #pragma unroll
        for (int n = 0; n < 4; ++n) acc[m][n] = (f32x4){0.f, 0.f, 0.f, 0.f};

    // prologue: stage tiles 0,1 -> slots 0,1 (3 loads each)
    #pragma unroll
    for (int tt = 0; tt < 2; ++tt) {
        STG(gA + tt * 32,    tt * SLOT9 + ldsA);
        STG(gB[0] + tt * 32, tt * SLOT9 + ldsB);
        STG(gB[1] + tt * 32, tt * SLOT9 + ldsB + 8192);
    }
    asm volatile("s_waitcnt vmcnt(3)" ::: "memory");
    __builtin_amdgcn_sched_barrier(0);
    __builtin_amdgcn_s_barrier();

    int cs = 0;
    #pragma unroll 1
    for (int t = 0; t < NT; ++t) {
        const char* sp = smem + cs * SLOT9;
        const bool pre = (t + 2) < NT;
        const int ss = ((cs == 0) ? 2 : cs - 1) * SLOT9;   // slot of (t+2)%3

        bf16x8 aF[4], bF[4];
        #pragma unroll
        for (int m = 0; m < 4; ++m) aF[m] = *(const bf16x8*)(sp + Aoff + m * 1024);
        #pragma unroll
        for (int n = 0; n < 4; ++n) bF[n] = *(const bf16x8*)(sp + Boff + n * 1024);
        if (pre) {
            STG(gA + (t + 2) * 32,    ss + ldsA);
            STG(gB[0] + (t + 2) * 32, ss + ldsB);
            STG(gB[1] + (t + 2) * 32, ss + ldsB + 8192);
        }
        __builtin_amdgcn_s_barrier();
        asm volatile("s_waitcnt lgkmcnt(0)" ::: "memory");
        __builtin_amdgcn_sched_barrier(0);
        __builtin_amdgcn_s_setprio(1);
        #pragma unroll
        for (int m = 0; m < 4; ++m)
            #pragma unroll
            for (int n = 0; n < 4; ++n)
                acc[m][n] = __builtin_amdgcn_mfma_f32_16x16x32_bf16(aF[m], bF[n], acc[m][n], 0, 0, 0);
        __builtin_amdgcn_s_setprio(0);
        if (pre) { asm volatile("s_waitcnt vmcnt(3)" ::: "memory"); }
        else     { asm volatile("s_waitcnt vmcnt(0)" ::: "memory"); }
        __builtin_amdgcn_sched_barrier(0);
        __builtin_amdgcn_s_barrier();
        cs = (cs == 2) ? 0 : cs + 1;
    }

    // epilogue: r = wr*64 + m*16 + (lane>>4)*4 + i, c = wc*64 + n*16 + (lane&15)
    #pragma unroll
    for (int m = 0; m < 4; ++m) {
        #pragma unroll
        for (int i = 0; i < 4; ++i) {
            int r  = wr * 64 + m * 16 + (lane >> 4) * 4 + i;
            int rr = base + r;
            if (rr < cnt) {
                if constexpr (UP) {
                    uint16_t* hr = hid_out + (size_t)(cofs + rr) * DFF + bn0 + wc * 64;
                    #pragma unroll
                    for (int n = 0; n < 4; ++n) {
                        float v = acc[m][n][i];
                        v = v > 0.f ? v : 0.f;
                        hr[n * 16 + (lane & 15)] = f2bf(v);
                    }
                } else {
                    float* orow = out + (size_t)permE[rr] * DMODEL + bn0 + wc * 64;
                    #pragma unroll
                    for (int n = 0; n < 4; ++n)
                        orow[n * 16 + (lane & 15)] = acc[m][n][i];
                }
            }
        }
    }
}

extern "C" void kernel_launch(void* const* d_in, const int* in_sizes, int n_in,
                              void* d_out, int out_size, void* d_ws, size_t ws_size,
                              hipStream_t stream) {
    const float* x     = (const float*)d_in[0];
    const float* Wup   = (const float*)d_in[1];
    const float* Wdown = (const float*)d_in[2];
    float* out  = (float*)d_out;
    float* gate = out + (size_t)NTOK * DMODEL;

    char* ws = (char*)d_ws;
    size_t off = 0;
    auto alloc = [&](size_t bytes) -> void* {
        void* p = ws + off;
        off += (bytes + 255) & ~(size_t)255;
        return p;
    };
    int*      counts  = (int*)alloc(NTILES * sizeof(int));
    float*    sig     = (float*)alloc((size_t)NTILES * DMODEL * sizeof(float));
    double*   partial = (double*)alloc((size_t)256 * NTILES * DMODEL * sizeof(double));
    int*      perm    = (int*)alloc((size_t)NTILES * NTOK * sizeof(int));
    uint16_t* xb      = (uint16_t*)alloc((size_t)NTOK * DMODEL * 2);
    uint16_t* wupb    = (uint16_t*)alloc((size_t)NTILES * DFF * DMODEL * 2);
    uint16_t* wdownb  = (uint16_t*)alloc((size_t)NTILES * DMODEL * DFF * 2);
    uint16_t* hidden  = (uint16_t*)alloc(((size_t)NTOK + 1024) * DFF * 2);
    if (off > ws_size) return;

    hipFuncSetAttribute((const void*)&k_ffn9<DMODEL, true>,
                        hipFuncAttributeMaxDynamicSharedMemorySize, 3 * SLOT9);
    hipFuncSetAttribute((const void*)&k_ffn9<DFF, false>,
                        hipFuncAttributeMaxDynamicSharedMemorySize, 3 * SLOT9);

    hipLaunchKernelGGL(k_convert, dim3(256, 4), dim3(256), 0, stream, Wup, wupb, partial);
    hipLaunchKernelGGL(k_sig_final, dim3(16), dim3(256), 0, stream, partial, sig, counts);
    hipLaunchKernelGGL(k_route, dim3(NTOK / 16), dim3(256), 0, stream,
                       x, sig, xb, gate, counts, perm);
    // UP GEMM + fused Wdown convert (y in [128,160) -> 4z*32*16x = 2048 chunks)
    hipLaunchKernelGGL((k_ffn9<DMODEL, true>), dim3(DFF / 256, YGEMM + 32, NTILES),
                       dim3(512), 3 * SLOT9, stream, xb, wupb, counts, perm, hidden, nullptr,
                       Wdown, wdownb);
    hipLaunchKernelGGL((k_ffn9<DFF, false>), dim3(DMODEL / 256, YGEMM, NTILES),
                       dim3(512), 3 * SLOT9, stream, hidden, wdownb, counts, perm, nullptr, out,
                       nullptr, nullptr);
}